// Round 10
// baseline (477.402 us; speedup 1.0000x reference)
//
#include <hip/hip_runtime.h>
#include <hip/hip_fp16.h>
#include <math.h>

#define IN_C   128
#define OUT_C  64
#define EDIM   16
#define EHID   32
#define GN_EPS 1e-5f

// DPAD reverted to 0: R9 proved padding is null for the atomic tax
// (k_edge identical 102us at 1 counter/64B-line) and costs ~9us in
// init/scan footprint. The ~100us k_edge cost is atomic SERVICE RATE.
#define DPAD 0

typedef unsigned long long u64;

__device__ __forceinline__ float dot4(float4 a, float4 b) {
    return a.x * b.x + a.y * b.y + a.z * b.z + a.w * b.w;
}
__device__ __forceinline__ void fma4(float4& a, float s, float4 w) {
    a.x = fmaf(s, w.x, a.x); a.y = fmaf(s, w.y, a.y);
    a.z = fmaf(s, w.z, a.z); a.w = fmaf(s, w.w, a.w);
}
__device__ __forceinline__ float getc(float4 v, int j) {
    return j == 0 ? v.x : j == 1 ? v.y : j == 2 ? v.z : v.w;
}

// ---------------------------------------------------------------------------
// K0: init  degcnt = {cnt:0, deg:1.0 fixed-point} (self-loop), sums = 0
// ---------------------------------------------------------------------------
__global__ void k_init(u64* __restrict__ degcnt, float* __restrict__ sums, int N) {
    int i = blockIdx.x * 256 + threadIdx.x;
    if (i < N) degcnt[(size_t)i << DPAD] = (1ull << 32);   // deg = 1.0 fixed point
    if (i < 2 * OUT_C) sums[i] = 0.f;
}

// ---------------------------------------------------------------------------
// K1: fused edge phase — R3/R8 structure. MLP (scalar-pipe weights, R5) ->
// ONE u64 RMW-with-return per thread issued AFTER the MLP.
// Atomic ledger: ~100us in ANY placement (R6 pure 77us; R7 fire-and-forget
// ~95; R7 rank-in-pass2 117; R9 line-padding null -> service-rate bound).
// Storms: u32 counters (R1) or >1 in-flight atomic/thread (R2) -> 20x
// traffic. u64 + 1/thread stable. DO NOT DEVIATE.
// tmp[e] = {row | rank<<17, ew}
// ---------------------------------------------------------------------------
__global__ void k_edge(const float* __restrict__ ea, const int* __restrict__ ei,
                       const float* __restrict__ w1, const float* __restrict__ b1,
                       const float* __restrict__ w2, const float* __restrict__ b2,
                       u64* __restrict__ degcnt, int2* __restrict__ tmp, int E) {
    int e = blockIdx.x * 256 + threadIdx.x;
    if (e >= E) return;

    const float4* eav = (const float4*)ea + (size_t)e * 4;
    float4 a0 = eav[0], a1 = eav[1], a2 = eav[2], a3 = eav[3];

    const float4* w1v = (const float4*)w1;    // wave-uniform -> s_load
    float z = b2[0];
    #pragma unroll
    for (int j = 0; j < EHID; ++j) {
        float4 q0 = w1v[j * 4 + 0];
        float4 q1 = w1v[j * 4 + 1];
        float4 q2 = w1v[j * 4 + 2];
        float4 q3 = w1v[j * 4 + 3];
        float h = dot4(a0, q0) + dot4(a1, q1) + dot4(a2, q2) + dot4(a3, q3) + b1[j];
        h = fmaxf(h, 0.f);
        z += h * w2[j];
    }
    float ewv = 1.f / (1.f + __expf(-z));

    int row = ei[e];
    int col = ei[E + e];
    u64 inc = (1ull << 44) | (u64)(ewv * 4294967296.0f);   // {cnt+=1, deg+=ew}
    u64 old = atomicAdd(&degcnt[(size_t)col << DPAD], inc);
    int rank = (int)(old >> 44);                            // edges before this one
    tmp[e] = make_int2(row | (rank << 17), __float_as_int(ewv));
}

// ---------------------------------------------------------------------------
// K2 (fallback path only): unpack degcnt -> dinv and cnt
// ---------------------------------------------------------------------------
__global__ void k_finish(const u64* __restrict__ degcnt, float* __restrict__ dinv,
                         int* __restrict__ cnt, int N) {
    int i = blockIdx.x * 256 + threadIdx.x;
    if (i < N) {
        u64 v = degcnt[(size_t)i << DPAD];
        float deg = (float)(v & ((1ull << 44) - 1)) * (1.f / 4294967296.f);
        dinv[i] = rsqrtf(deg);                    // deg >= 1 always
        cnt[i] = (int)(v >> 44);
    }
}

// ---------------------------------------------------------------------------
// scan1 (CSR path): fused k_finish + block-local exclusive scan of cnt.
// full_start(i) = start[i] + bsums[i>>8]  (scan3 fused into consumers)
// ---------------------------------------------------------------------------
__global__ void k_scan1(const u64* __restrict__ degcnt, int* __restrict__ start,
                        int* __restrict__ bsums, float* __restrict__ dinv,
                        int* __restrict__ cnt, int N) {
    __shared__ int s[256];
    int t = threadIdx.x;
    int i = blockIdx.x * 256 + t;
    int v = 0;
    if (i < N) {
        u64 dv = degcnt[(size_t)i << DPAD];
        v = (int)(dv >> 44);
        float deg = (float)(dv & ((1ull << 44) - 1)) * (1.f / 4294967296.f);
        dinv[i] = rsqrtf(deg);
        cnt[i] = v;
    }
    s[t] = v;
    __syncthreads();
    #pragma unroll
    for (int off = 1; off < 256; off <<= 1) {
        int u = (t >= off) ? s[t - off] : 0;
        __syncthreads();
        s[t] += u;
        __syncthreads();
    }
    if (i < N) start[i] = s[t] - v;
    if (t == 255) bsums[blockIdx.x] = s[255];
}
__global__ void k_scan2(int* __restrict__ bsums, int nb) {
    __shared__ int s[1024];
    int t = threadIdx.x;
    s[t] = (t < nb) ? bsums[t] : 0;
    __syncthreads();
    #pragma unroll
    for (int off = 1; off < 1024; off <<= 1) {
        int u = (t >= off) ? s[t - off] : 0;
        __syncthreads();
        s[t] += u;
        __syncthreads();
    }
    if (t < nb) bsums[t] = (t == 0) ? 0 : s[t - 1];
}

// ---------------------------------------------------------------------------
// pass2: atomic-free permute — rec[full_start[col]+rank] = {row, ew}.
// rec stores are AGENT-SCOPE (combine partial 64B lines at the shared LLC
// instead of per-XCD L2 partial-dirty writebacks; R7 measured 101MB HBM
// writes for this 12.8MB buffer). Kept this round (R9's padding masked its
// effect); R10-vs-R8 total signs it cleanly.
// ---------------------------------------------------------------------------
__global__ void k_pass2(const int* __restrict__ ei, const int2* __restrict__ tmp,
                        const int* __restrict__ start, const int* __restrict__ bsums,
                        u64* __restrict__ rec, int E) {
    int e = blockIdx.x * 256 + threadIdx.x;
    if (e >= E) return;
    int col = ei[E + e];
    int2 t = tmp[e];
    int rank = ((unsigned)t.x) >> 17;
    int pos = start[col] + bsums[col >> 8] + rank;
    u64 v = (u64)(unsigned)(t.x & 0x1FFFF) | ((u64)(unsigned)t.y << 32);
    __hip_atomic_store(&rec[pos], v, __ATOMIC_RELAXED, __HIP_MEMORY_SCOPE_AGENT);
}

// ---------------------------------------------------------------------------
// K3: xts = dinv * (x @ lin_w^T) stored as FP16 (R8)
// ---------------------------------------------------------------------------
__global__ void k_xt(const float* __restrict__ x, const float* __restrict__ lw,
                     const float* __restrict__ dinv, __half* __restrict__ xts, int N) {
    __shared__ float swt[IN_C * OUT_C];
    int tid = threadIdx.x;
    for (int i = tid; i < IN_C * OUT_C; i += 256) {
        int k = i >> 6, c = i & 63;
        swt[i] = lw[c * IN_C + k];
    }
    __syncthreads();

    int lane = tid & 63;
    int c4 = lane & 15;
    int rq = lane >> 4;
    int rbase = blockIdx.x * 64 + (tid >> 6) * 16 + rq * 4;

    int r0 = min(rbase + 0, N - 1), r1 = min(rbase + 1, N - 1);
    int r2 = min(rbase + 2, N - 1), r3 = min(rbase + 3, N - 1);
    const float4* x4 = (const float4*)x;
    float4 acc0 = {0,0,0,0}, acc1 = {0,0,0,0}, acc2 = {0,0,0,0}, acc3 = {0,0,0,0};

    #pragma unroll 4
    for (int k4 = 0; k4 < IN_C / 4; ++k4) {
        float4 xv0 = x4[(size_t)r0 * 32 + k4];
        float4 xv1 = x4[(size_t)r1 * 32 + k4];
        float4 xv2 = x4[(size_t)r2 * 32 + k4];
        float4 xv3 = x4[(size_t)r3 * 32 + k4];
        #pragma unroll
        for (int j = 0; j < 4; ++j) {
            float4 wv = *(const float4*)&swt[(k4 * 4 + j) * OUT_C + (c4 << 2)];
            fma4(acc0, getc(xv0, j), wv);
            fma4(acc1, getc(xv1, j), wv);
            fma4(acc2, getc(xv2, j), wv);
            fma4(acc3, getc(xv3, j), wv);
        }
    }
    int cc = c4 << 2;
    #pragma unroll
    for (int i = 0; i < 4; ++i) {
        int r = rbase + i;
        if (r < N) {
            float d = dinv[r];
            float4 a = i == 0 ? acc0 : i == 1 ? acc1 : i == 2 ? acc2 : acc3;
            union { __half2 h[2]; uint2 u; } cv;
            cv.h[0] = __floats2half2_rn(a.x * d, a.y * d);
            cv.h[1] = __floats2half2_rn(a.z * d, a.w * d);
            *(uint2*)&xts[(size_t)r * OUT_C + cc] = cv.u;
        }
    }
}

// ---------------------------------------------------------------------------
// gather (GRID-STRIDE, fused PReLU + GraphNorm stats): 2048 blocks loop over
// node-quads; thread-local s,s2 accumulate across all nodes; ONE LDS reduce
// + 128 float atomics per block (262K total over 128 addrs ~ 3us — the
// naive 25000-block fusion would be 3.2M same-addr atomics ~ 40us).
// out stores y = PReLU(v); k_apply_csr skips the PReLU recompute.
// Saves the separate k_stats pass (25.6MB read + launch).
// ---------------------------------------------------------------------------
__global__ void k_gather(const u64* __restrict__ rec, const int* __restrict__ start,
                         const int* __restrict__ bsums, const int* __restrict__ cnt,
                         const float* __restrict__ dinv, const __half* __restrict__ xts,
                         const float* __restrict__ bias, const float* __restrict__ pa,
                         float* __restrict__ out, float* __restrict__ sums, int N) {
    __shared__ float r1[256], r2[256];
    int tid  = threadIdx.x;
    int lane = tid & 63;
    float a = pa[0];
    float bl = bias[lane];
    float s = 0.f, s2 = 0.f;

    int ngroups = (N + 3) >> 2;
    for (int g = blockIdx.x; g < ngroups; g += gridDim.x) {
        int node = g * 4 + (tid >> 6);
        if (node < N) {
            int beg = start[node] + bsums[node >> 8];
            int num = cnt[node];
            float acc = __half2float(xts[((size_t)node << 6) + lane]); // self-loop
            int j = 0;
            for (; j + 8 <= num; j += 8) {
                u64 rc[8];
                #pragma unroll
                for (int u = 0; u < 8; ++u) rc[u] = rec[beg + j + u];
                float v[8];
                #pragma unroll
                for (int u = 0; u < 8; ++u)
                    v[u] = __half2float(xts[((size_t)(unsigned)(rc[u] & 0x1FFFF) << 6) + lane]);
                #pragma unroll
                for (int u = 0; u < 8; ++u)
                    acc = fmaf(__int_as_float((int)(rc[u] >> 32)), v[u], acc);
            }
            for (; j < num; ++j) {
                u64 rc = rec[beg + j];
                acc = fmaf(__int_as_float((int)(rc >> 32)),
                           __half2float(xts[((size_t)(unsigned)(rc & 0x1FFFF) << 6) + lane]), acc);
            }
            float v = bl + dinv[node] * acc;
            float y = v >= 0.f ? v : a * v;
            out[((size_t)node << 6) + lane] = y;
            s += y; s2 += y * y;
        }
    }

    r1[tid] = s; r2[tid] = s2;
    __syncthreads();
    if (tid < 64) {
        float t1 = r1[tid] + r1[tid + 64] + r1[tid + 128] + r1[tid + 192];
        float t2 = r2[tid] + r2[tid + 64] + r2[tid + 128] + r2[tid + 192];
        atomicAdd(&sums[tid], t1);
        atomicAdd(&sums[OUT_C + tid], t2);
    }
}

// ---------------------------------------------------------------------------
// fallback (emergency, if ws too small for rec): atomic scatter path
// ---------------------------------------------------------------------------
__global__ void k_init_out(const float* __restrict__ bias, const float* __restrict__ dinv,
                           const __half* __restrict__ xts, float* __restrict__ out, int total) {
    int t = blockIdx.x * 256 + threadIdx.x;
    if (t >= total) return;
    int i = t >> 6, c = t & 63;
    out[t] = bias[c] + dinv[i] * __half2float(xts[t]);
}
__global__ void k_scatter(const int* __restrict__ ei, const int2* __restrict__ tmp,
                          const float* __restrict__ dinv, const __half* __restrict__ xts,
                          float* __restrict__ out, int E) {
    int t = blockIdx.x * 256 + threadIdx.x;
    int e = t >> 6;
    if (e >= E) return;
    int lane = t & 63;
    int2 tm = tmp[e];
    int row = tm.x & 0x1FFFF;
    int col = ei[E + e];
    float w = dinv[col] * __int_as_float(tm.y);
    atomicAdd(out + (size_t)col * OUT_C + lane,
              w * __half2float(xts[(size_t)row * OUT_C + lane]));
}
__global__ void k_stats(const float* __restrict__ out, const float* __restrict__ pa,
                        float* __restrict__ sums, int total) {
    __shared__ float r1[256], r2[256];
    float a = pa[0];
    float s = 0.f, s2 = 0.f;
    int stride = gridDim.x * 256;
    for (int t = blockIdx.x * 256 + threadIdx.x; t < total; t += stride) {
        float v = out[t];
        float y = v >= 0.f ? v : a * v;
        s += y; s2 += y * y;
    }
    int tid = threadIdx.x;
    r1[tid] = s; r2[tid] = s2;
    __syncthreads();
    if (tid < 64) {
        float t1 = r1[tid] + r1[tid + 64] + r1[tid + 128] + r1[tid + 192];
        float t2 = r2[tid] + r2[tid + 64] + r2[tid + 128] + r2[tid + 192];
        atomicAdd(&sums[tid], t1);
        atomicAdd(&sums[OUT_C + tid], t2);
    }
}

// ---------------------------------------------------------------------------
// apply — CSR variant: out already holds y = PReLU(v)
// ---------------------------------------------------------------------------
__global__ void k_apply_csr(float* __restrict__ out, const float* __restrict__ sums,
                            const float* __restrict__ gw, const float* __restrict__ gb,
                            const float* __restrict__ gms, int total, float invN) {
    int t = blockIdx.x * 256 + threadIdx.x;
    if (t >= total) return;
    int c = t & 63;
    float m  = sums[c] * invN;
    float ms = gms[c];
    float var = sums[OUT_C + c] * invN - ms * m * m * (2.f - ms);
    float A = gw[c] * rsqrtf(var + GN_EPS);
    float y = out[t];
    out[t] = A * (y - ms * m) + gb[c];
}
// apply — fallback variant: out holds raw v (pre-PReLU)
__global__ void k_apply_fb(float* __restrict__ out, const float* __restrict__ pa,
                           const float* __restrict__ sums,
                           const float* __restrict__ gw, const float* __restrict__ gb,
                           const float* __restrict__ gms, int total, float invN) {
    int t = blockIdx.x * 256 + threadIdx.x;
    if (t >= total) return;
    int c = t & 63;
    float a  = pa[0];
    float m  = sums[c] * invN;
    float ms = gms[c];
    float var = sums[OUT_C + c] * invN - ms * m * m * (2.f - ms);
    float A = gw[c] * rsqrtf(var + GN_EPS);
    float v = out[t];
    float y = v >= 0.f ? v : a * v;
    out[t] = A * (y - ms * m) + gb[c];
}

// ---------------------------------------------------------------------------
extern "C" void kernel_launch(void* const* d_in, const int* in_sizes, int n_in,
                              void* d_out, int out_size, void* d_ws, size_t ws_size,
                              hipStream_t stream) {
    (void)n_in; (void)out_size;
    const float* x    = (const float*)d_in[0];
    const int*   ei   = (const int*)  d_in[1];   // [2,E] row-major int32
    const float* ea   = (const float*)d_in[2];
    const float* lw   = (const float*)d_in[3];
    const float* bias = (const float*)d_in[4];
    const float* w1   = (const float*)d_in[5];
    const float* b1   = (const float*)d_in[6];
    const float* w2   = (const float*)d_in[7];
    const float* b2   = (const float*)d_in[8];
    const float* pa   = (const float*)d_in[9];
    const float* gw   = (const float*)d_in[10];
    const float* gb   = (const float*)d_in[11];
    const float* gms  = (const float*)d_in[12];
    float* out = (float*)d_out;

    int N = in_sizes[0] / IN_C;
    int E = in_sizes[2] / EDIM;
    int total = N * OUT_C;
    int nbN = (N + 255) / 256;
    int nbE = (E + 255) / 256;

    // workspace layout (degcnt first for 8B alignment; rec LAST for fallback)
    char* p = (char*)d_ws;
    u64*   degcnt = (u64*)p;  p += sizeof(u64) * ((size_t)N << DPAD);
    float* dinv   = (float*)p; p += sizeof(float) * (size_t)N;
    __half* xts   = (__half*)p; p += sizeof(__half) * (size_t)N * OUT_C;
    float* sums   = (float*)p; p += sizeof(float) * 128;
    int*   cnt    = (int*)p;   p += sizeof(int) * (size_t)N;
    int*   startv = (int*)p;   p += sizeof(int) * (size_t)N;
    int*   bsums  = (int*)p;   p += sizeof(int) * 1024;
    int2*  tmp    = (int2*)p;  p += sizeof(int2) * (size_t)E;
    u64*   rec    = (u64*)p;   p += sizeof(u64) * (size_t)E;
    size_t need = (size_t)(p - (char*)d_ws);
    bool use_csr = (need <= ws_size) && (nbN <= 1024);

    k_init <<<nbN, 256, 0, stream>>>(degcnt, sums, N);
    k_edge <<<nbE, 256, 0, stream>>>(ea, ei, w1, b1, w2, b2, degcnt, tmp, E);

    if (use_csr) {
        int ngroups = (N + 3) >> 2;
        int gblocks = ngroups < 2048 ? ngroups : 2048;
        k_scan1 <<<nbN, 256, 0, stream>>>(degcnt, startv, bsums, dinv, cnt, N);
        k_scan2 <<<1, 1024, 0, stream>>>(bsums, nbN);
        k_pass2 <<<nbE, 256, 0, stream>>>(ei, tmp, startv, bsums, rec, E);
        k_xt    <<<(N + 63) / 64, 256, 0, stream>>>(x, lw, dinv, xts, N);
        k_gather<<<gblocks, 256, 0, stream>>>(rec, startv, bsums, cnt, dinv, xts,
                                              bias, pa, out, sums, N);
        k_apply_csr<<<(total + 255) / 256, 256, 0, stream>>>(out, sums, gw, gb, gms,
                                                             total, 1.0f / (float)N);
    } else {
        k_finish<<<nbN, 256, 0, stream>>>(degcnt, dinv, cnt, N);
        k_xt    <<<(N + 63) / 64, 256, 0, stream>>>(x, lw, dinv, xts, N);
        k_init_out<<<(total + 255) / 256, 256, 0, stream>>>(bias, dinv, xts, out, total);
        long st = (long)E * 64;
        k_scatter <<<(unsigned)((st + 255) / 256), 256, 0, stream>>>(ei, tmp, dinv, xts, out, E);
        k_stats <<<512, 256, 0, stream>>>(out, pa, sums, total);
        k_apply_fb<<<(total + 255) / 256, 256, 0, stream>>>(out, pa, sums, gw, gb, gms,
                                                            total, 1.0f / (float)N);
    }
}

// Round 11
// 449.081 us; speedup vs baseline: 1.0631x; 1.0631x over previous
//
#include <hip/hip_runtime.h>
#include <hip/hip_fp16.h>
#include <math.h>

#define IN_C   128
#define OUT_C  64
#define EDIM   16
#define EHID   32
#define GN_EPS 1e-5f
#define MAXDEG 48          // Poisson(16) tail: P(deg>48) ~ 1e-9/node; overflow handled
#define OVFCAP 2048

typedef unsigned long long u64;

__device__ __forceinline__ float dot4(float4 a, float4 b) {
    return a.x * b.x + a.y * b.y + a.z * b.z + a.w * b.w;
}
__device__ __forceinline__ void fma4(float4& a, float s, float4 w) {
    a.x = fmaf(s, w.x, a.x); a.y = fmaf(s, w.y, a.y);
    a.z = fmaf(s, w.z, a.z); a.w = fmaf(s, w.w, a.w);
}
__device__ __forceinline__ float getc(float4 v, int j) {
    return j == 0 ? v.x : j == 1 ? v.y : j == 2 ? v.z : v.w;
}

// ---------------------------------------------------------------------------
// K0: init  degcnt = {cnt:0, deg:1.0 fixed-point} (self-loop), sums=0, ovf=0
// ---------------------------------------------------------------------------
__global__ void k_init(u64* __restrict__ degcnt, float* __restrict__ sums,
                       u64* __restrict__ ovfcnt, int N) {
    int i = blockIdx.x * 256 + threadIdx.x;
    if (i < N) degcnt[i] = (1ull << 32);          // deg = 1.0 in 2^32 fixed point
    if (i < 2 * OUT_C) sums[i] = 0.f;
    if (i == 0) *ovfcnt = 0ull;
}

// ---------------------------------------------------------------------------
// K1 (CSR-direct): MLP (scalar-pipe weights, R5) -> ONE u64 RMW-with-return
// per thread AFTER the MLP -> store the edge record DIRECTLY at its final
// CSR slot rec[col*MAXDEG + rank]. This deletes tmp, scan1, scan2, pass2
// (~75-115us of passes): the rank atomic already assigns the slot; the old
// pipeline only existed to compute start[] offsets a fixed stride makes
// unnecessary. Store is AGENT-SCOPE: ~8 XCDs write partial 64B lines of the
// same node row (R7 measured 8x write-amp for exactly this pattern).
// Atomic ledger: ~100us in ANY placement (R6 77 pure / R7 95 f&f / R7 117
// pass2 / R9 padding null -> service-rate bound). Storms: u32 counters (R1),
// >1 in-flight atomic/thread (R2). u64 + 1/thread + post-MLP. DO NOT DEVIATE.
// Overflow (rank>=MAXDEG, ~never): append {row,col,ew} to ovf list.
// ---------------------------------------------------------------------------
__global__ void k_edge(const float* __restrict__ ea, const int* __restrict__ ei,
                       const float* __restrict__ w1, const float* __restrict__ b1,
                       const float* __restrict__ w2, const float* __restrict__ b2,
                       u64* __restrict__ degcnt, u64* __restrict__ rec,
                       u64* __restrict__ ovfcnt, int4* __restrict__ ovflist, int E) {
    int e = blockIdx.x * 256 + threadIdx.x;
    if (e >= E) return;

    const float4* eav = (const float4*)ea + (size_t)e * 4;
    float4 a0 = eav[0], a1 = eav[1], a2 = eav[2], a3 = eav[3];

    const float4* w1v = (const float4*)w1;    // wave-uniform -> s_load
    float z = b2[0];
    #pragma unroll
    for (int j = 0; j < EHID; ++j) {
        float4 q0 = w1v[j * 4 + 0];
        float4 q1 = w1v[j * 4 + 1];
        float4 q2 = w1v[j * 4 + 2];
        float4 q3 = w1v[j * 4 + 3];
        float h = dot4(a0, q0) + dot4(a1, q1) + dot4(a2, q2) + dot4(a3, q3) + b1[j];
        h = fmaxf(h, 0.f);
        z += h * w2[j];
    }
    float ewv = 1.f / (1.f + __expf(-z));

    int row = ei[e];
    int col = ei[E + e];
    u64 inc = (1ull << 44) | (u64)(ewv * 4294967296.0f);   // {cnt+=1, deg+=ew}
    u64 old = atomicAdd(&degcnt[col], inc);
    int rank = (int)(old >> 44);                            // this edge's CSR slot
    if (rank < MAXDEG) {
        u64 v = (u64)(unsigned)row | ((u64)(unsigned)__float_as_int(ewv) << 32);
        __hip_atomic_store(&rec[(size_t)col * MAXDEG + rank], v,
                           __ATOMIC_RELAXED, __HIP_MEMORY_SCOPE_AGENT);
    } else {
        u64 oi = atomicAdd(ovfcnt, 1ull);                   // ~never taken
        if (oi < OVFCAP) ovflist[oi] = make_int4(row, col, __float_as_int(ewv), 0);
    }
}

// ---------------------------------------------------------------------------
// K1-fallback: old tmp-writing form (for the atomic-scatter fallback path)
// ---------------------------------------------------------------------------
__global__ void k_edge_fb(const float* __restrict__ ea, const int* __restrict__ ei,
                          const float* __restrict__ w1, const float* __restrict__ b1,
                          const float* __restrict__ w2, const float* __restrict__ b2,
                          u64* __restrict__ degcnt, int2* __restrict__ tmp, int E) {
    int e = blockIdx.x * 256 + threadIdx.x;
    if (e >= E) return;
    const float4* eav = (const float4*)ea + (size_t)e * 4;
    float4 a0 = eav[0], a1 = eav[1], a2 = eav[2], a3 = eav[3];
    const float4* w1v = (const float4*)w1;
    float z = b2[0];
    #pragma unroll
    for (int j = 0; j < EHID; ++j) {
        float4 q0 = w1v[j * 4 + 0];
        float4 q1 = w1v[j * 4 + 1];
        float4 q2 = w1v[j * 4 + 2];
        float4 q3 = w1v[j * 4 + 3];
        float h = dot4(a0, q0) + dot4(a1, q1) + dot4(a2, q2) + dot4(a3, q3) + b1[j];
        h = fmaxf(h, 0.f);
        z += h * w2[j];
    }
    float ewv = 1.f / (1.f + __expf(-z));
    int row = ei[e];
    int col = ei[E + e];
    u64 inc = (1ull << 44) | (u64)(ewv * 4294967296.0f);
    u64 old = atomicAdd(&degcnt[col], inc);
    int rank = (int)(old >> 44);
    tmp[e] = make_int2(row | (rank << 17), __float_as_int(ewv));
}

// ---------------------------------------------------------------------------
// K2: unpack degcnt -> dinv and gather-count (capped at MAXDEG)
// ---------------------------------------------------------------------------
__global__ void k_finish(const u64* __restrict__ degcnt, float* __restrict__ dinv,
                         int* __restrict__ cnt, int N) {
    int i = blockIdx.x * 256 + threadIdx.x;
    if (i < N) {
        u64 v = degcnt[i];
        float deg = (float)(v & ((1ull << 44) - 1)) * (1.f / 4294967296.f);
        dinv[i] = rsqrtf(deg);                    // deg >= 1 always
        int c = (int)(v >> 44);
        cnt[i] = c < MAXDEG ? c : MAXDEG;
    }
}

// ---------------------------------------------------------------------------
// K3: xts = dinv * (x @ lin_w^T) stored as FP16 (R8)
// ---------------------------------------------------------------------------
__global__ void k_xt(const float* __restrict__ x, const float* __restrict__ lw,
                     const float* __restrict__ dinv, __half* __restrict__ xts, int N) {
    __shared__ float swt[IN_C * OUT_C];
    int tid = threadIdx.x;
    for (int i = tid; i < IN_C * OUT_C; i += 256) {
        int k = i >> 6, c = i & 63;
        swt[i] = lw[c * IN_C + k];
    }
    __syncthreads();

    int lane = tid & 63;
    int c4 = lane & 15;
    int rq = lane >> 4;
    int rbase = blockIdx.x * 64 + (tid >> 6) * 16 + rq * 4;

    int r0 = min(rbase + 0, N - 1), r1 = min(rbase + 1, N - 1);
    int r2 = min(rbase + 2, N - 1), r3 = min(rbase + 3, N - 1);
    const float4* x4 = (const float4*)x;
    float4 acc0 = {0,0,0,0}, acc1 = {0,0,0,0}, acc2 = {0,0,0,0}, acc3 = {0,0,0,0};

    #pragma unroll 4
    for (int k4 = 0; k4 < IN_C / 4; ++k4) {
        float4 xv0 = x4[(size_t)r0 * 32 + k4];
        float4 xv1 = x4[(size_t)r1 * 32 + k4];
        float4 xv2 = x4[(size_t)r2 * 32 + k4];
        float4 xv3 = x4[(size_t)r3 * 32 + k4];
        #pragma unroll
        for (int j = 0; j < 4; ++j) {
            float4 wv = *(const float4*)&swt[(k4 * 4 + j) * OUT_C + (c4 << 2)];
            fma4(acc0, getc(xv0, j), wv);
            fma4(acc1, getc(xv1, j), wv);
            fma4(acc2, getc(xv2, j), wv);
            fma4(acc3, getc(xv3, j), wv);
        }
    }
    int cc = c4 << 2;
    #pragma unroll
    for (int i = 0; i < 4; ++i) {
        int r = rbase + i;
        if (r < N) {
            float d = dinv[r];
            float4 a = i == 0 ? acc0 : i == 1 ? acc1 : i == 2 ? acc2 : acc3;
            union { __half2 h[2]; uint2 u; } cv;
            cv.h[0] = __floats2half2_rn(a.x * d, a.y * d);
            cv.h[1] = __floats2half2_rn(a.z * d, a.w * d);
            *(uint2*)&xts[(size_t)r * OUT_C + cc] = cv.u;
        }
    }
}

// ---------------------------------------------------------------------------
// gather (R8 shape: one wave per node, 4 nodes/block — the R10 grid-stride
// fusion regressed ~15us, reverted). rec row = rec[node*MAXDEG ...], still
// contiguous per node. out = bias + dinv[node]*(sum ew_j*xts[row_j] + self)
// ---------------------------------------------------------------------------
__global__ void k_gather(const u64* __restrict__ rec, const int* __restrict__ cnt,
                         const float* __restrict__ dinv, const __half* __restrict__ xts,
                         const float* __restrict__ bias, float* __restrict__ out, int N) {
    int node = blockIdx.x * 4 + (threadIdx.x >> 6);
    if (node >= N) return;
    int lane = threadIdx.x & 63;
    int beg = node * MAXDEG;
    int num = cnt[node];
    float acc = __half2float(xts[((size_t)node << 6) + lane]);   // self-loop term
    int j = 0;
    for (; j + 8 <= num; j += 8) {
        u64 rc[8];
        #pragma unroll
        for (int u = 0; u < 8; ++u) rc[u] = rec[beg + j + u];
        float v[8];
        #pragma unroll
        for (int u = 0; u < 8; ++u)
            v[u] = __half2float(xts[((size_t)(unsigned)(rc[u] & 0x1FFFF) << 6) + lane]);
        #pragma unroll
        for (int u = 0; u < 8; ++u)
            acc = fmaf(__int_as_float((int)(rc[u] >> 32)), v[u], acc);
    }
    for (; j < num; ++j) {
        u64 rc = rec[beg + j];
        acc = fmaf(__int_as_float((int)(rc >> 32)),
                   __half2float(xts[((size_t)(unsigned)(rc & 0x1FFFF) << 6) + lane]), acc);
    }
    out[((size_t)node << 6) + lane] = bias[lane] + dinv[node] * acc;
}

// ---------------------------------------------------------------------------
// k_ovf: add rare overflow edges (rank >= MAXDEG) into out. Expected 0
// iterations; correctness guarantee for the fixed-stride CSR.
// ---------------------------------------------------------------------------
__global__ void k_ovf(const int4* __restrict__ ovflist, const u64* __restrict__ ovfcnt,
                      const float* __restrict__ dinv, const __half* __restrict__ xts,
                      float* __restrict__ out) {
    u64 nv = *ovfcnt;
    int n = nv > (u64)OVFCAP ? OVFCAP : (int)nv;
    int lane = threadIdx.x & 63;
    for (int i = blockIdx.x * 4 + (threadIdx.x >> 6); i < n; i += gridDim.x * 4) {
        int4 v = ovflist[i];
        float w = dinv[v.y] * __int_as_float(v.z);
        atomicAdd(&out[(size_t)v.y * OUT_C + lane],
                  w * __half2float(xts[(size_t)v.x * OUT_C + lane]));
    }
}

// ---------------------------------------------------------------------------
// fallback (emergency, if ws too small): atomic scatter path
// ---------------------------------------------------------------------------
__global__ void k_init_out(const float* __restrict__ bias, const float* __restrict__ dinv,
                           const __half* __restrict__ xts, float* __restrict__ out, int total) {
    int t = blockIdx.x * 256 + threadIdx.x;
    if (t >= total) return;
    int i = t >> 6, c = t & 63;
    out[t] = bias[c] + dinv[i] * __half2float(xts[t]);
}
__global__ void k_scatter(const int* __restrict__ ei, const int2* __restrict__ tmp,
                          const float* __restrict__ dinv, const __half* __restrict__ xts,
                          float* __restrict__ out, int E) {
    int t = blockIdx.x * 256 + threadIdx.x;
    int e = t >> 6;
    if (e >= E) return;
    int lane = t & 63;
    int2 tm = tmp[e];
    int row = tm.x & 0x1FFFF;
    int col = ei[E + e];
    float w = dinv[col] * __int_as_float(tm.y);
    atomicAdd(out + (size_t)col * OUT_C + lane,
              w * __half2float(xts[(size_t)row * OUT_C + lane]));
}

// ---------------------------------------------------------------------------
// PReLU + GraphNorm stats + apply (R8 forms; out holds raw v)
// ---------------------------------------------------------------------------
__global__ void k_stats(const float* __restrict__ out, const float* __restrict__ pa,
                        float* __restrict__ sums, int total) {
    __shared__ float r1[256], r2[256];
    float a = pa[0];
    float s = 0.f, s2 = 0.f;
    int stride = gridDim.x * 256;
    for (int t = blockIdx.x * 256 + threadIdx.x; t < total; t += stride) {
        float v = out[t];
        float y = v >= 0.f ? v : a * v;
        s += y; s2 += y * y;
    }
    int tid = threadIdx.x;
    r1[tid] = s; r2[tid] = s2;
    __syncthreads();
    if (tid < 64) {
        float t1 = r1[tid] + r1[tid + 64] + r1[tid + 128] + r1[tid + 192];
        float t2 = r2[tid] + r2[tid + 64] + r2[tid + 128] + r2[tid + 192];
        atomicAdd(&sums[tid], t1);
        atomicAdd(&sums[OUT_C + tid], t2);
    }
}
__global__ void k_apply(float* __restrict__ out, const float* __restrict__ pa,
                        const float* __restrict__ sums,
                        const float* __restrict__ gw, const float* __restrict__ gb,
                        const float* __restrict__ gms, int total, float invN) {
    int t = blockIdx.x * 256 + threadIdx.x;
    if (t >= total) return;
    int c = t & 63;
    float a  = pa[0];
    float m  = sums[c] * invN;
    float ms = gms[c];
    float var = sums[OUT_C + c] * invN - ms * m * m * (2.f - ms);
    float A = gw[c] * rsqrtf(var + GN_EPS);
    float v = out[t];
    float y = v >= 0.f ? v : a * v;
    out[t] = A * (y - ms * m) + gb[c];
}

// ---------------------------------------------------------------------------
extern "C" void kernel_launch(void* const* d_in, const int* in_sizes, int n_in,
                              void* d_out, int out_size, void* d_ws, size_t ws_size,
                              hipStream_t stream) {
    (void)n_in; (void)out_size;
    const float* x    = (const float*)d_in[0];
    const int*   ei   = (const int*)  d_in[1];   // [2,E] row-major int32
    const float* ea   = (const float*)d_in[2];
    const float* lw   = (const float*)d_in[3];
    const float* bias = (const float*)d_in[4];
    const float* w1   = (const float*)d_in[5];
    const float* b1   = (const float*)d_in[6];
    const float* w2   = (const float*)d_in[7];
    const float* b2   = (const float*)d_in[8];
    const float* pa   = (const float*)d_in[9];
    const float* gw   = (const float*)d_in[10];
    const float* gb   = (const float*)d_in[11];
    const float* gms  = (const float*)d_in[12];
    float* out = (float*)d_out;

    int N = in_sizes[0] / IN_C;
    int E = in_sizes[2] / EDIM;
    int total = N * OUT_C;
    int nbN = (N + 255) / 256;
    int nbE = (E + 255) / 256;

    // common prefix
    char* p = (char*)d_ws;
    u64*   degcnt = (u64*)p;  p += sizeof(u64) * (size_t)N;
    float* dinv   = (float*)p; p += sizeof(float) * (size_t)N;
    __half* xts   = (__half*)p; p += sizeof(__half) * (size_t)N * OUT_C;
    float* sums   = (float*)p; p += sizeof(float) * 128;
    int*   cnt    = (int*)p;   p += sizeof(int) * (size_t)N;
    char*  tail = p;
    // CSR-direct layout
    u64*   ovfcnt  = (u64*)tail;
    int4*  ovflist = (int4*)(tail + sizeof(u64) * 2);
    u64*   rec     = (u64*)(tail + sizeof(u64) * 2 + sizeof(int4) * OVFCAP);
    size_t need_csr = (size_t)((char*)(rec + (size_t)N * MAXDEG) - (char*)d_ws);
    // fallback layout (aliases tail)
    int2*  tmp = (int2*)tail;
    size_t need_fb = (size_t)((char*)(tmp + (size_t)E) - (char*)d_ws);
    bool use_csr = (need_csr <= ws_size) && (N < (1 << 17));

    if (use_csr) {
        k_init  <<<nbN, 256, 0, stream>>>(degcnt, sums, ovfcnt, N);
        k_edge  <<<nbE, 256, 0, stream>>>(ea, ei, w1, b1, w2, b2, degcnt,
                                          rec, ovfcnt, ovflist, E);
        k_finish<<<nbN, 256, 0, stream>>>(degcnt, dinv, cnt, N);
        k_xt    <<<(N + 63) / 64, 256, 0, stream>>>(x, lw, dinv, xts, N);
        k_gather<<<(N + 3) / 4, 256, 0, stream>>>(rec, cnt, dinv, xts, bias, out, N);
        k_ovf   <<<64, 256, 0, stream>>>(ovflist, ovfcnt, dinv, xts, out);
        k_stats <<<512, 256, 0, stream>>>(out, pa, sums, total);
        k_apply <<<(total + 255) / 256, 256, 0, stream>>>(out, pa, sums, gw, gb, gms,
                                                          total, 1.0f / (float)N);
    } else {
        (void)need_fb;
        k_init   <<<nbN, 256, 0, stream>>>(degcnt, sums, (u64*)sums /*dummy*/, N);
        k_edge_fb<<<nbE, 256, 0, stream>>>(ea, ei, w1, b1, w2, b2, degcnt, tmp, E);
        k_finish <<<nbN, 256, 0, stream>>>(degcnt, dinv, cnt, N);
        k_xt     <<<(N + 63) / 64, 256, 0, stream>>>(x, lw, dinv, xts, N);
        k_init_out<<<(total + 255) / 256, 256, 0, stream>>>(bias, dinv, xts, out, total);
        long st = (long)E * 64;
        k_scatter <<<(unsigned)((st + 255) / 256), 256, 0, stream>>>(ei, tmp, dinv, xts, out, E);
        k_stats  <<<512, 256, 0, stream>>>(out, pa, sums, total);
        k_apply  <<<(total + 255) / 256, 256, 0, stream>>>(out, pa, sums, gw, gb, gms,
                                                           total, 1.0f / (float)N);
    }
}

// Round 12
// 423.611 us; speedup vs baseline: 1.1270x; 1.0601x over previous
//
#include <hip/hip_runtime.h>
#include <hip/hip_fp16.h>
#include <math.h>

#define IN_C   128
#define OUT_C  64
#define EDIM   16
#define EHID   32
#define GN_EPS 1e-5f
#define MAXDEG 48          // Poisson(16) tail: P(deg>48) ~ 1e-9/node; overflow handled
#define OVFCAP 2048

typedef unsigned long long u64;
typedef unsigned int u32;

__device__ __forceinline__ float dot4(float4 a, float4 b) {
    return a.x * b.x + a.y * b.y + a.z * b.z + a.w * b.w;
}
__device__ __forceinline__ void fma4(float4& a, float s, float4 w) {
    a.x = fmaf(s, w.x, a.x); a.y = fmaf(s, w.y, a.y);
    a.z = fmaf(s, w.z, a.z); a.w = fmaf(s, w.w, a.w);
}
__device__ __forceinline__ float getc(float4 v, int j) {
    return j == 0 ? v.x : j == 1 ? v.y : j == 2 ? v.z : v.w;
}
__device__ __forceinline__ float deg_from(u64 v) {
    return (float)(v & ((1ull << 44) - 1)) * (1.f / 4294967296.f);
}

// ---------------------------------------------------------------------------
// K0: init  degcnt = {cnt:0, deg:1.0 fixed-point} (self-loop), sums=0, ovf=0
// ---------------------------------------------------------------------------
__global__ void k_init(u64* __restrict__ degcnt, float* __restrict__ sums,
                       u64* __restrict__ ovfcnt, int N) {
    int i = blockIdx.x * 256 + threadIdx.x;
    if (i < N) degcnt[i] = (1ull << 32);          // deg = 1.0 in 2^32 fixed point
    if (i < 2 * OUT_C) sums[i] = 0.f;
    if (i == 0) *ovfcnt = 0ull;
}

// ---------------------------------------------------------------------------
// K1 (CSR-direct, R11-proven): MLP (scalar-pipe weights, R5) -> ONE u64
// RMW-with-return per thread AFTER the MLP -> store record at its final CSR
// slot rec[col*MAXDEG + rank] (agent-scope). Deletes tmp/scan/pass2.
// Atomic ledger: ~100us in ANY placement; service-rate bound (R9). Storms:
// u32 counters (R1), >1 in-flight atomic/thread (R2). DO NOT DEVIATE.
// ---------------------------------------------------------------------------
__global__ void k_edge(const float* __restrict__ ea, const int* __restrict__ ei,
                       const float* __restrict__ w1, const float* __restrict__ b1,
                       const float* __restrict__ w2, const float* __restrict__ b2,
                       u64* __restrict__ degcnt, u64* __restrict__ rec,
                       u64* __restrict__ ovfcnt, int4* __restrict__ ovflist, int E) {
    int e = blockIdx.x * 256 + threadIdx.x;
    if (e >= E) return;

    const float4* eav = (const float4*)ea + (size_t)e * 4;
    float4 a0 = eav[0], a1 = eav[1], a2 = eav[2], a3 = eav[3];

    const float4* w1v = (const float4*)w1;    // wave-uniform -> s_load
    float z = b2[0];
    #pragma unroll
    for (int j = 0; j < EHID; ++j) {
        float4 q0 = w1v[j * 4 + 0];
        float4 q1 = w1v[j * 4 + 1];
        float4 q2 = w1v[j * 4 + 2];
        float4 q3 = w1v[j * 4 + 3];
        float h = dot4(a0, q0) + dot4(a1, q1) + dot4(a2, q2) + dot4(a3, q3) + b1[j];
        h = fmaxf(h, 0.f);
        z += h * w2[j];
    }
    float ewv = 1.f / (1.f + __expf(-z));

    int row = ei[e];
    int col = ei[E + e];
    u64 inc = (1ull << 44) | (u64)(ewv * 4294967296.0f);   // {cnt+=1, deg+=ew}
    u64 old = atomicAdd(&degcnt[col], inc);
    int rank = (int)(old >> 44);                            // this edge's CSR slot
    if (rank < MAXDEG) {
        u64 v = (u64)(unsigned)row | ((u64)(unsigned)__float_as_int(ewv) << 32);
        __hip_atomic_store(&rec[(size_t)col * MAXDEG + rank], v,
                           __ATOMIC_RELAXED, __HIP_MEMORY_SCOPE_AGENT);
    } else {
        u64 oi = atomicAdd(ovfcnt, 1ull);                   // ~never taken
        if (oi < OVFCAP) ovflist[oi] = make_int4(row, col, __float_as_int(ewv), 0);
    }
}

// ---------------------------------------------------------------------------
// K1-fallback: old tmp-writing form (for the atomic-scatter fallback path)
// ---------------------------------------------------------------------------
__global__ void k_edge_fb(const float* __restrict__ ea, const int* __restrict__ ei,
                          const float* __restrict__ w1, const float* __restrict__ b1,
                          const float* __restrict__ w2, const float* __restrict__ b2,
                          u64* __restrict__ degcnt, int2* __restrict__ tmp, int E) {
    int e = blockIdx.x * 256 + threadIdx.x;
    if (e >= E) return;
    const float4* eav = (const float4*)ea + (size_t)e * 4;
    float4 a0 = eav[0], a1 = eav[1], a2 = eav[2], a3 = eav[3];
    const float4* w1v = (const float4*)w1;
    float z = b2[0];
    #pragma unroll
    for (int j = 0; j < EHID; ++j) {
        float4 q0 = w1v[j * 4 + 0];
        float4 q1 = w1v[j * 4 + 1];
        float4 q2 = w1v[j * 4 + 2];
        float4 q3 = w1v[j * 4 + 3];
        float h = dot4(a0, q0) + dot4(a1, q1) + dot4(a2, q2) + dot4(a3, q3) + b1[j];
        h = fmaxf(h, 0.f);
        z += h * w2[j];
    }
    float ewv = 1.f / (1.f + __expf(-z));
    int row = ei[e];
    int col = ei[E + e];
    u64 inc = (1ull << 44) | (u64)(ewv * 4294967296.0f);
    u64 old = atomicAdd(&degcnt[col], inc);
    int rank = (int)(old >> 44);
    tmp[e] = make_int2(row | (rank << 17), __float_as_int(ewv));
}

// ---------------------------------------------------------------------------
// K2 (fallback path only now): unpack degcnt -> dinv and cnt
// ---------------------------------------------------------------------------
__global__ void k_finish(const u64* __restrict__ degcnt, float* __restrict__ dinv,
                         int* __restrict__ cnt, int N) {
    int i = blockIdx.x * 256 + threadIdx.x;
    if (i < N) {
        u64 v = degcnt[i];
        dinv[i] = rsqrtf(deg_from(v));
        int c = (int)(v >> 44);
        cnt[i] = c < MAXDEG ? c : MAXDEG;
    }
}

// ---------------------------------------------------------------------------
// K3: xts = dinv * (x @ lin_w^T) stored FP16. dinv unpacked INLINE from
// degcnt (k_finish deleted from CSR path — saves a full-N pass + launch).
// ---------------------------------------------------------------------------
__global__ void k_xt(const float* __restrict__ x, const float* __restrict__ lw,
                     const u64* __restrict__ degcnt, __half* __restrict__ xts, int N) {
    __shared__ float swt[IN_C * OUT_C];
    int tid = threadIdx.x;
    for (int i = tid; i < IN_C * OUT_C; i += 256) {
        int k = i >> 6, c = i & 63;
        swt[i] = lw[c * IN_C + k];
    }
    __syncthreads();

    int lane = tid & 63;
    int c4 = lane & 15;
    int rq = lane >> 4;
    int rbase = blockIdx.x * 64 + (tid >> 6) * 16 + rq * 4;

    int r0 = min(rbase + 0, N - 1), r1 = min(rbase + 1, N - 1);
    int r2 = min(rbase + 2, N - 1), r3 = min(rbase + 3, N - 1);
    const float4* x4 = (const float4*)x;
    float4 acc0 = {0,0,0,0}, acc1 = {0,0,0,0}, acc2 = {0,0,0,0}, acc3 = {0,0,0,0};

    #pragma unroll 4
    for (int k4 = 0; k4 < IN_C / 4; ++k4) {
        float4 xv0 = x4[(size_t)r0 * 32 + k4];
        float4 xv1 = x4[(size_t)r1 * 32 + k4];
        float4 xv2 = x4[(size_t)r2 * 32 + k4];
        float4 xv3 = x4[(size_t)r3 * 32 + k4];
        #pragma unroll
        for (int j = 0; j < 4; ++j) {
            float4 wv = *(const float4*)&swt[(k4 * 4 + j) * OUT_C + (c4 << 2)];
            fma4(acc0, getc(xv0, j), wv);
            fma4(acc1, getc(xv1, j), wv);
            fma4(acc2, getc(xv2, j), wv);
            fma4(acc3, getc(xv3, j), wv);
        }
    }
    int cc = c4 << 2;
    #pragma unroll
    for (int i = 0; i < 4; ++i) {
        int r = rbase + i;
        if (r < N) {
            float d = rsqrtf(deg_from(degcnt[r]));
            float4 a = i == 0 ? acc0 : i == 1 ? acc1 : i == 2 ? acc2 : acc3;
            union { __half2 h[2]; uint2 u; } cv;
            cv.h[0] = __floats2half2_rn(a.x * d, a.y * d);
            cv.h[1] = __floats2half2_rn(a.z * d, a.w * d);
            *(uint2*)&xts[(size_t)r * OUT_C + cc] = cv.u;
        }
    }
}

// ---------------------------------------------------------------------------
// gather (2 NODES PER WAVE, half2 per lane): R8/R10 proved gather is
// latency/instruction-bound, not byte-bound (fp16 halving -5us; 17% VALU).
// Lanes 0-31 take node A, 32-63 node B; each lane owns 2 channels via one
// 4B half2 load -> load instructions per node halve, per-lane ILP doubles.
// Divergence cost only E[max(numA,numB)] ~ 18.3 vs 16 iters. cnt/dinv
// unpacked inline from degcnt (8B broadcast per half-wave).
// ---------------------------------------------------------------------------
__global__ void k_gather(const u64* __restrict__ rec, const u64* __restrict__ degcnt,
                         const u32* __restrict__ xtsu, const float2* __restrict__ bias2,
                         float2* __restrict__ out2, int N) {
    int tid  = threadIdx.x;
    int lane = tid & 63;
    int node = blockIdx.x * 8 + ((tid >> 6) << 1) + (lane >> 5);
    if (node >= N) return;
    int sl = lane & 31;                       // sub-lane: channels 2sl, 2sl+1

    u64 dv = degcnt[node];
    int num = (int)(dv >> 44);
    num = num < MAXDEG ? num : MAXDEG;
    float dinv = rsqrtf(deg_from(dv));
    size_t beg = (size_t)node * MAXDEG;

    u32 selfv = xtsu[((size_t)node << 5) + sl];
    float2 sf = __half22float2(*(__half2*)&selfv);
    float acc0 = sf.x, acc1 = sf.y;           // self-loop term

    int j = 0;
    for (; j + 8 <= num; j += 8) {
        u64 rc[8];
        #pragma unroll
        for (int u = 0; u < 8; ++u) rc[u] = rec[beg + j + u];
        u32 v[8];
        #pragma unroll
        for (int u = 0; u < 8; ++u)
            v[u] = xtsu[((size_t)(u32)rc[u] << 5) + sl];
        #pragma unroll
        for (int u = 0; u < 8; ++u) {
            float w = __int_as_float((int)(rc[u] >> 32));
            float2 f = __half22float2(*(__half2*)&v[u]);
            acc0 = fmaf(w, f.x, acc0);
            acc1 = fmaf(w, f.y, acc1);
        }
    }
    for (; j < num; ++j) {
        u64 rc = rec[beg + j];
        u32 v = xtsu[((size_t)(u32)rc << 5) + sl];
        float w = __int_as_float((int)(rc >> 32));
        float2 f = __half22float2(*(__half2*)&v);
        acc0 = fmaf(w, f.x, acc0);
        acc1 = fmaf(w, f.y, acc1);
    }
    float2 b = bias2[sl];
    out2[((size_t)node << 5) + sl] = make_float2(b.x + dinv * acc0, b.y + dinv * acc1);
}

// ---------------------------------------------------------------------------
// k_ovf: add rare overflow edges (rank >= MAXDEG) into out. Expected 0 iters.
// ---------------------------------------------------------------------------
__global__ void k_ovf(const int4* __restrict__ ovflist, const u64* __restrict__ ovfcnt,
                      const u64* __restrict__ degcnt, const __half* __restrict__ xts,
                      float* __restrict__ out) {
    u64 nv = *ovfcnt;
    int n = nv > (u64)OVFCAP ? OVFCAP : (int)nv;
    int lane = threadIdx.x & 63;
    for (int i = blockIdx.x * 4 + (threadIdx.x >> 6); i < n; i += gridDim.x * 4) {
        int4 v = ovflist[i];
        float w = rsqrtf(deg_from(degcnt[v.y])) * __int_as_float(v.z);
        atomicAdd(&out[(size_t)v.y * OUT_C + lane],
                  w * __half2float(xts[(size_t)v.x * OUT_C + lane]));
    }
}

// ---------------------------------------------------------------------------
// fallback (emergency, if ws too small): atomic scatter path
// ---------------------------------------------------------------------------
__global__ void k_init_out(const float* __restrict__ bias, const float* __restrict__ dinv,
                           const __half* __restrict__ xts, float* __restrict__ out, int total) {
    int t = blockIdx.x * 256 + threadIdx.x;
    if (t >= total) return;
    int i = t >> 6, c = t & 63;
    out[t] = bias[c] + dinv[i] * __half2float(xts[t]);
}
__global__ void k_scatter(const int* __restrict__ ei, const int2* __restrict__ tmp,
                          const float* __restrict__ dinv, const __half* __restrict__ xts,
                          float* __restrict__ out, int E) {
    int t = blockIdx.x * 256 + threadIdx.x;
    int e = t >> 6;
    if (e >= E) return;
    int lane = t & 63;
    int2 tm = tmp[e];
    int row = tm.x & 0x1FFFF;
    int col = ei[E + e];
    float w = dinv[col] * __int_as_float(tm.y);
    atomicAdd(out + (size_t)col * OUT_C + lane,
              w * __half2float(xts[(size_t)row * OUT_C + lane]));
}

// ---------------------------------------------------------------------------
// PReLU + GraphNorm stats + apply (out holds raw v)
// ---------------------------------------------------------------------------
__global__ void k_stats(const float* __restrict__ out, const float* __restrict__ pa,
                        float* __restrict__ sums, int total) {
    __shared__ float r1[256], r2[256];
    float a = pa[0];
    float s = 0.f, s2 = 0.f;
    int stride = gridDim.x * 256;
    for (int t = blockIdx.x * 256 + threadIdx.x; t < total; t += stride) {
        float v = out[t];
        float y = v >= 0.f ? v : a * v;
        s += y; s2 += y * y;
    }
    int tid = threadIdx.x;
    r1[tid] = s; r2[tid] = s2;
    __syncthreads();
    if (tid < 64) {
        float t1 = r1[tid] + r1[tid + 64] + r1[tid + 128] + r1[tid + 192];
        float t2 = r2[tid] + r2[tid + 64] + r2[tid + 128] + r2[tid + 192];
        atomicAdd(&sums[tid], t1);
        atomicAdd(&sums[OUT_C + tid], t2);
    }
}
__global__ void k_apply(float* __restrict__ out, const float* __restrict__ pa,
                        const float* __restrict__ sums,
                        const float* __restrict__ gw, const float* __restrict__ gb,
                        const float* __restrict__ gms, int total, float invN) {
    int t = blockIdx.x * 256 + threadIdx.x;
    if (t >= total) return;
    int c = t & 63;
    float a  = pa[0];
    float m  = sums[c] * invN;
    float ms = gms[c];
    float var = sums[OUT_C + c] * invN - ms * m * m * (2.f - ms);
    float A = gw[c] * rsqrtf(var + GN_EPS);
    float v = out[t];
    float y = v >= 0.f ? v : a * v;
    out[t] = A * (y - ms * m) + gb[c];
}

// ---------------------------------------------------------------------------
extern "C" void kernel_launch(void* const* d_in, const int* in_sizes, int n_in,
                              void* d_out, int out_size, void* d_ws, size_t ws_size,
                              hipStream_t stream) {
    (void)n_in; (void)out_size;
    const float* x    = (const float*)d_in[0];
    const int*   ei   = (const int*)  d_in[1];   // [2,E] row-major int32
    const float* ea   = (const float*)d_in[2];
    const float* lw   = (const float*)d_in[3];
    const float* bias = (const float*)d_in[4];
    const float* w1   = (const float*)d_in[5];
    const float* b1   = (const float*)d_in[6];
    const float* w2   = (const float*)d_in[7];
    const float* b2   = (const float*)d_in[8];
    const float* pa   = (const float*)d_in[9];
    const float* gw   = (const float*)d_in[10];
    const float* gb   = (const float*)d_in[11];
    const float* gms  = (const float*)d_in[12];
    float* out = (float*)d_out;

    int N = in_sizes[0] / IN_C;
    int E = in_sizes[2] / EDIM;
    int total = N * OUT_C;
    int nbN = (N + 255) / 256;
    int nbE = (E + 255) / 256;

    // common prefix
    char* p = (char*)d_ws;
    u64*   degcnt = (u64*)p;  p += sizeof(u64) * (size_t)N;
    float* dinv   = (float*)p; p += sizeof(float) * (size_t)N;
    __half* xts   = (__half*)p; p += sizeof(__half) * (size_t)N * OUT_C;
    float* sums   = (float*)p; p += sizeof(float) * 128;
    int*   cnt    = (int*)p;   p += sizeof(int) * (size_t)N;
    char*  tail = p;
    // CSR-direct layout
    u64*   ovfcnt  = (u64*)tail;
    int4*  ovflist = (int4*)(tail + sizeof(u64) * 2);
    u64*   rec     = (u64*)(tail + sizeof(u64) * 2 + sizeof(int4) * OVFCAP);
    size_t need_csr = (size_t)((char*)(rec + (size_t)N * MAXDEG) - (char*)d_ws);
    // fallback layout (aliases tail)
    int2*  tmp = (int2*)tail;
    bool use_csr = (need_csr <= ws_size);

    if (use_csr) {
        k_init  <<<nbN, 256, 0, stream>>>(degcnt, sums, ovfcnt, N);
        k_edge  <<<nbE, 256, 0, stream>>>(ea, ei, w1, b1, w2, b2, degcnt,
                                          rec, ovfcnt, ovflist, E);
        k_xt    <<<(N + 63) / 64, 256, 0, stream>>>(x, lw, degcnt, xts, N);
        k_gather<<<(N + 7) / 8, 256, 0, stream>>>(rec, degcnt, (const u32*)xts,
                                                  (const float2*)bias, (float2*)out, N);
        k_ovf   <<<64, 256, 0, stream>>>(ovflist, ovfcnt, degcnt, xts, out);
        k_stats <<<512, 256, 0, stream>>>(out, pa, sums, total);
        k_apply <<<(total + 255) / 256, 256, 0, stream>>>(out, pa, sums, gw, gb, gms,
                                                          total, 1.0f / (float)N);
    } else {
        k_init   <<<nbN, 256, 0, stream>>>(degcnt, sums, (u64*)sums /*dummy*/, N);
        k_edge_fb<<<nbE, 256, 0, stream>>>(ea, ei, w1, b1, w2, b2, degcnt, tmp, E);
        k_finish <<<nbN, 256, 0, stream>>>(degcnt, dinv, cnt, N);
        k_xt_fb: ;
        // fallback keeps dinv-based xt via a tiny shim: reuse k_xt with degcnt
        k_xt     <<<(N + 63) / 64, 256, 0, stream>>>(x, lw, degcnt, xts, N);
        k_init_out<<<(total + 255) / 256, 256, 0, stream>>>(bias, dinv, xts, out, total);
        long st = (long)E * 64;
        k_scatter <<<(unsigned)((st + 255) / 256), 256, 0, stream>>>(ei, tmp, dinv, xts, out, E);
        k_stats  <<<512, 256, 0, stream>>>(out, pa, sums, total);
        k_apply  <<<(total + 255) / 256, 256, 0, stream>>>(out, pa, sums, gw, gb, gms,
                                                           total, 1.0f / (float)N);
    }
}

// Round 13
// 414.401 us; speedup vs baseline: 1.1520x; 1.0222x over previous
//
#include <hip/hip_runtime.h>
#include <hip/hip_fp16.h>
#include <math.h>

#define IN_C   128
#define OUT_C  64
#define EDIM   16
#define EHID   32
#define GN_EPS 1e-5f
#define MAXDEG 48          // Poisson(16) tail: P(deg>48) ~ 1e-9/node; overflow handled
#define OVFCAP 2048

typedef unsigned long long u64;
typedef unsigned int u32;

__device__ __forceinline__ float dot4(float4 a, float4 b) {
    return a.x * b.x + a.y * b.y + a.z * b.z + a.w * b.w;
}
__device__ __forceinline__ void fma4(float4& a, float s, float4 w) {
    a.x = fmaf(s, w.x, a.x); a.y = fmaf(s, w.y, a.y);
    a.z = fmaf(s, w.z, a.z); a.w = fmaf(s, w.w, a.w);
}
__device__ __forceinline__ float getc(float4 v, int j) {
    return j == 0 ? v.x : j == 1 ? v.y : j == 2 ? v.z : v.w;
}
__device__ __forceinline__ float deg_from(u64 v) {
    return (float)(v & ((1ull << 44) - 1)) * (1.f / 4294967296.f);
}

// ---------------------------------------------------------------------------
// K0: init  degcnt = {cnt:0, deg:1.0 fixed-point} (self-loop), sums=0, ovf=0
// ---------------------------------------------------------------------------
__global__ void k_init(u64* __restrict__ degcnt, float* __restrict__ sums,
                       u64* __restrict__ ovfcnt, int N) {
    int i = blockIdx.x * 256 + threadIdx.x;
    if (i < N) degcnt[i] = (1ull << 32);          // deg = 1.0 in 2^32 fixed point
    if (i < 2 * OUT_C) sums[i] = 0.f;
    if (i == 0) *ovfcnt = 0ull;
}

// ---------------------------------------------------------------------------
// K1 (CSR-direct, R11): MLP (scalar-pipe weights, R5) -> ONE u64
// RMW-with-return per thread AFTER the MLP -> store record at its final CSR
// slot rec[col*MAXDEG + rank] (agent-scope). rec entry is now u32
// {row:17 | q15(ew)<<17} (R13): halves scattered-store payload (node row
// 6 -> 3 lines, less multi-XCD partial-line amp) and gather's rec bytes.
// ew quantization err <= 2^-16 -> out err ~1e-5, tolerance 0.03. deg uses
// exact ew via the atomic.
// Atomic ledger: ~100us in ANY placement; service-rate bound (R9). Storms:
// u32 counters (R1), >1 in-flight atomic/thread (R2). DO NOT DEVIATE.
// ---------------------------------------------------------------------------
__global__ void k_edge(const float* __restrict__ ea, const int* __restrict__ ei,
                       const float* __restrict__ w1, const float* __restrict__ b1,
                       const float* __restrict__ w2, const float* __restrict__ b2,
                       u64* __restrict__ degcnt, u32* __restrict__ rec,
                       u64* __restrict__ ovfcnt, int4* __restrict__ ovflist, int E) {
    int e = blockIdx.x * 256 + threadIdx.x;
    if (e >= E) return;

    const float4* eav = (const float4*)ea + (size_t)e * 4;
    float4 a0 = eav[0], a1 = eav[1], a2 = eav[2], a3 = eav[3];

    const float4* w1v = (const float4*)w1;    // wave-uniform -> s_load
    float z = b2[0];
    #pragma unroll
    for (int j = 0; j < EHID; ++j) {
        float4 q0 = w1v[j * 4 + 0];
        float4 q1 = w1v[j * 4 + 1];
        float4 q2 = w1v[j * 4 + 2];
        float4 q3 = w1v[j * 4 + 3];
        float h = dot4(a0, q0) + dot4(a1, q1) + dot4(a2, q2) + dot4(a3, q3) + b1[j];
        h = fmaxf(h, 0.f);
        z += h * w2[j];
    }
    float ewv = 1.f / (1.f + __expf(-z));

    int row = ei[e];
    int col = ei[E + e];
    u64 inc = (1ull << 44) | (u64)(ewv * 4294967296.0f);   // {cnt+=1, deg+=ew}
    u64 old = atomicAdd(&degcnt[col], inc);
    int rank = (int)(old >> 44);                            // this edge's CSR slot
    if (rank < MAXDEG) {
        u32 q = (u32)__float2uint_rn(ewv * 32768.f);
        q = q > 32767u ? 32767u : q;
        u32 v = (u32)row | (q << 17);
        __hip_atomic_store(&rec[(size_t)col * MAXDEG + rank], v,
                           __ATOMIC_RELAXED, __HIP_MEMORY_SCOPE_AGENT);
    } else {
        u64 oi = atomicAdd(ovfcnt, 1ull);                   // ~never taken
        if (oi < OVFCAP) ovflist[oi] = make_int4(row, col, __float_as_int(ewv), 0);
    }
}

// ---------------------------------------------------------------------------
// K1-fallback: old tmp-writing form (for the atomic-scatter fallback path)
// ---------------------------------------------------------------------------
__global__ void k_edge_fb(const float* __restrict__ ea, const int* __restrict__ ei,
                          const float* __restrict__ w1, const float* __restrict__ b1,
                          const float* __restrict__ w2, const float* __restrict__ b2,
                          u64* __restrict__ degcnt, int2* __restrict__ tmp, int E) {
    int e = blockIdx.x * 256 + threadIdx.x;
    if (e >= E) return;
    const float4* eav = (const float4*)ea + (size_t)e * 4;
    float4 a0 = eav[0], a1 = eav[1], a2 = eav[2], a3 = eav[3];
    const float4* w1v = (const float4*)w1;
    float z = b2[0];
    #pragma unroll
    for (int j = 0; j < EHID; ++j) {
        float4 q0 = w1v[j * 4 + 0];
        float4 q1 = w1v[j * 4 + 1];
        float4 q2 = w1v[j * 4 + 2];
        float4 q3 = w1v[j * 4 + 3];
        float h = dot4(a0, q0) + dot4(a1, q1) + dot4(a2, q2) + dot4(a3, q3) + b1[j];
        h = fmaxf(h, 0.f);
        z += h * w2[j];
    }
    float ewv = 1.f / (1.f + __expf(-z));
    int row = ei[e];
    int col = ei[E + e];
    u64 inc = (1ull << 44) | (u64)(ewv * 4294967296.0f);
    u64 old = atomicAdd(&degcnt[col], inc);
    int rank = (int)(old >> 44);
    tmp[e] = make_int2(row | (rank << 17), __float_as_int(ewv));
}

// ---------------------------------------------------------------------------
// K2 (fallback path only): unpack degcnt -> dinv and cnt
// ---------------------------------------------------------------------------
__global__ void k_finish(const u64* __restrict__ degcnt, float* __restrict__ dinv,
                         int* __restrict__ cnt, int N) {
    int i = blockIdx.x * 256 + threadIdx.x;
    if (i < N) {
        u64 v = degcnt[i];
        dinv[i] = rsqrtf(deg_from(v));
        int c = (int)(v >> 44);
        cnt[i] = c < MAXDEG ? c : MAXDEG;
    }
}

// ---------------------------------------------------------------------------
// K3: xts = dinv * (x @ lin_w^T) stored FP16; dinv unpacked inline (R12)
// ---------------------------------------------------------------------------
__global__ void k_xt(const float* __restrict__ x, const float* __restrict__ lw,
                     const u64* __restrict__ degcnt, __half* __restrict__ xts, int N) {
    __shared__ float swt[IN_C * OUT_C];
    int tid = threadIdx.x;
    for (int i = tid; i < IN_C * OUT_C; i += 256) {
        int k = i >> 6, c = i & 63;
        swt[i] = lw[c * IN_C + k];
    }
    __syncthreads();

    int lane = tid & 63;
    int c4 = lane & 15;
    int rq = lane >> 4;
    int rbase = blockIdx.x * 64 + (tid >> 6) * 16 + rq * 4;

    int r0 = min(rbase + 0, N - 1), r1 = min(rbase + 1, N - 1);
    int r2 = min(rbase + 2, N - 1), r3 = min(rbase + 3, N - 1);
    const float4* x4 = (const float4*)x;
    float4 acc0 = {0,0,0,0}, acc1 = {0,0,0,0}, acc2 = {0,0,0,0}, acc3 = {0,0,0,0};

    #pragma unroll 4
    for (int k4 = 0; k4 < IN_C / 4; ++k4) {
        float4 xv0 = x4[(size_t)r0 * 32 + k4];
        float4 xv1 = x4[(size_t)r1 * 32 + k4];
        float4 xv2 = x4[(size_t)r2 * 32 + k4];
        float4 xv3 = x4[(size_t)r3 * 32 + k4];
        #pragma unroll
        for (int j = 0; j < 4; ++j) {
            float4 wv = *(const float4*)&swt[(k4 * 4 + j) * OUT_C + (c4 << 2)];
            fma4(acc0, getc(xv0, j), wv);
            fma4(acc1, getc(xv1, j), wv);
            fma4(acc2, getc(xv2, j), wv);
            fma4(acc3, getc(xv3, j), wv);
        }
    }
    int cc = c4 << 2;
    #pragma unroll
    for (int i = 0; i < 4; ++i) {
        int r = rbase + i;
        if (r < N) {
            float d = rsqrtf(deg_from(degcnt[r]));
            float4 a = i == 0 ? acc0 : i == 1 ? acc1 : i == 2 ? acc2 : acc3;
            union { __half2 h[2]; uint2 u; } cv;
            cv.h[0] = __floats2half2_rn(a.x * d, a.y * d);
            cv.h[1] = __floats2half2_rn(a.z * d, a.w * d);
            *(uint2*)&xts[(size_t)r * OUT_C + cc] = cv.u;
        }
    }
}

// ---------------------------------------------------------------------------
// gather (4 NODES PER WAVE, 16 lanes/node, 4 channels/lane via uint2):
// R12's instruction-halving gained 25us -> push further. Per-wave iters =
// E[max of 4 Poisson(16)] ~ 20.2 serving 4 nodes = 5.05 iter-equiv/node
// (vs 9.15 at 2-node). rec load per node-group is a 16-lane broadcast of
// one u32; xts load 8B/lane coalesced. rec entry u32 {row:17|q15<<17}.
// ---------------------------------------------------------------------------
__global__ void k_gather(const u32* __restrict__ rec, const u64* __restrict__ degcnt,
                         const uint2* __restrict__ xtsu2, const float4* __restrict__ bias4,
                         float4* __restrict__ out4, int N) {
    int tid  = threadIdx.x;
    int lane = tid & 63;
    int node = blockIdx.x * 16 + ((tid >> 6) << 2) + (lane >> 4);
    if (node >= N) return;
    int sl = lane & 15;                       // channels 4sl .. 4sl+3

    u64 dv = degcnt[node];
    int num = (int)(dv >> 44);
    num = num < MAXDEG ? num : MAXDEG;
    float dinv = rsqrtf(deg_from(dv));
    size_t beg = (size_t)node * MAXDEG;

    uint2 selfv = xtsu2[((size_t)node << 4) + sl];
    float2 s0 = __half22float2(*(__half2*)&selfv.x);
    float2 s1 = __half22float2(*(__half2*)&selfv.y);
    float acc0 = s0.x, acc1 = s0.y, acc2 = s1.x, acc3 = s1.y;   // self-loop

    int j = 0;
    for (; j + 8 <= num; j += 8) {
        u32 rc[8];
        #pragma unroll
        for (int u = 0; u < 8; ++u) rc[u] = rec[beg + j + u];
        uint2 v[8];
        #pragma unroll
        for (int u = 0; u < 8; ++u)
            v[u] = xtsu2[((size_t)(rc[u] & 0x1FFFF) << 4) + sl];
        #pragma unroll
        for (int u = 0; u < 8; ++u) {
            float w = (float)(rc[u] >> 17) * (1.f / 32768.f);
            float2 f0 = __half22float2(*(__half2*)&v[u].x);
            float2 f1 = __half22float2(*(__half2*)&v[u].y);
            acc0 = fmaf(w, f0.x, acc0);
            acc1 = fmaf(w, f0.y, acc1);
            acc2 = fmaf(w, f1.x, acc2);
            acc3 = fmaf(w, f1.y, acc3);
        }
    }
    for (; j < num; ++j) {
        u32 rc = rec[beg + j];
        uint2 v = xtsu2[((size_t)(rc & 0x1FFFF) << 4) + sl];
        float w = (float)(rc >> 17) * (1.f / 32768.f);
        float2 f0 = __half22float2(*(__half2*)&v.x);
        float2 f1 = __half22float2(*(__half2*)&v.y);
        acc0 = fmaf(w, f0.x, acc0);
        acc1 = fmaf(w, f0.y, acc1);
        acc2 = fmaf(w, f1.x, acc2);
        acc3 = fmaf(w, f1.y, acc3);
    }
    float4 b = bias4[sl];
    out4[((size_t)node << 4) + sl] =
        make_float4(b.x + dinv * acc0, b.y + dinv * acc1,
                    b.z + dinv * acc2, b.w + dinv * acc3);
}

// ---------------------------------------------------------------------------
// k_ovf: add rare overflow edges (rank >= MAXDEG) into out. Expected 0 iters.
// ---------------------------------------------------------------------------
__global__ void k_ovf(const int4* __restrict__ ovflist, const u64* __restrict__ ovfcnt,
                      const u64* __restrict__ degcnt, const __half* __restrict__ xts,
                      float* __restrict__ out) {
    u64 nv = *ovfcnt;
    int n = nv > (u64)OVFCAP ? OVFCAP : (int)nv;
    int lane = threadIdx.x & 63;
    for (int i = blockIdx.x * 4 + (threadIdx.x >> 6); i < n; i += gridDim.x * 4) {
        int4 v = ovflist[i];
        float w = rsqrtf(deg_from(degcnt[v.y])) * __int_as_float(v.z);
        atomicAdd(&out[(size_t)v.y * OUT_C + lane],
                  w * __half2float(xts[(size_t)v.x * OUT_C + lane]));
    }
}

// ---------------------------------------------------------------------------
// fallback (emergency, if ws too small): atomic scatter path
// ---------------------------------------------------------------------------
__global__ void k_init_out(const float* __restrict__ bias, const float* __restrict__ dinv,
                           const __half* __restrict__ xts, float* __restrict__ out, int total) {
    int t = blockIdx.x * 256 + threadIdx.x;
    if (t >= total) return;
    int i = t >> 6, c = t & 63;
    out[t] = bias[c] + dinv[i] * __half2float(xts[t]);
}
__global__ void k_scatter(const int* __restrict__ ei, const int2* __restrict__ tmp,
                          const float* __restrict__ dinv, const __half* __restrict__ xts,
                          float* __restrict__ out, int E) {
    int t = blockIdx.x * 256 + threadIdx.x;
    int e = t >> 6;
    if (e >= E) return;
    int lane = t & 63;
    int2 tm = tmp[e];
    int row = tm.x & 0x1FFFF;
    int col = ei[E + e];
    float w = dinv[col] * __int_as_float(tm.y);
    atomicAdd(out + (size_t)col * OUT_C + lane,
              w * __half2float(xts[(size_t)row * OUT_C + lane]));
}

// ---------------------------------------------------------------------------
// PReLU + GraphNorm stats + apply (out holds raw v)
// ---------------------------------------------------------------------------
__global__ void k_stats(const float* __restrict__ out, const float* __restrict__ pa,
                        float* __restrict__ sums, int total) {
    __shared__ float r1[256], r2[256];
    float a = pa[0];
    float s = 0.f, s2 = 0.f;
    int stride = gridDim.x * 256;
    for (int t = blockIdx.x * 256 + threadIdx.x; t < total; t += stride) {
        float v = out[t];
        float y = v >= 0.f ? v : a * v;
        s += y; s2 += y * y;
    }
    int tid = threadIdx.x;
    r1[tid] = s; r2[tid] = s2;
    __syncthreads();
    if (tid < 64) {
        float t1 = r1[tid] + r1[tid + 64] + r1[tid + 128] + r1[tid + 192];
        float t2 = r2[tid] + r2[tid + 64] + r2[tid + 128] + r2[tid + 192];
        atomicAdd(&sums[tid], t1);
        atomicAdd(&sums[OUT_C + tid], t2);
    }
}
__global__ void k_apply(float* __restrict__ out, const float* __restrict__ pa,
                        const float* __restrict__ sums,
                        const float* __restrict__ gw, const float* __restrict__ gb,
                        const float* __restrict__ gms, int total, float invN) {
    int t = blockIdx.x * 256 + threadIdx.x;
    if (t >= total) return;
    int c = t & 63;
    float a  = pa[0];
    float m  = sums[c] * invN;
    float ms = gms[c];
    float var = sums[OUT_C + c] * invN - ms * m * m * (2.f - ms);
    float A = gw[c] * rsqrtf(var + GN_EPS);
    float v = out[t];
    float y = v >= 0.f ? v : a * v;
    out[t] = A * (y - ms * m) + gb[c];
}

// ---------------------------------------------------------------------------
extern "C" void kernel_launch(void* const* d_in, const int* in_sizes, int n_in,
                              void* d_out, int out_size, void* d_ws, size_t ws_size,
                              hipStream_t stream) {
    (void)n_in; (void)out_size;
    const float* x    = (const float*)d_in[0];
    const int*   ei   = (const int*)  d_in[1];   // [2,E] row-major int32
    const float* ea   = (const float*)d_in[2];
    const float* lw   = (const float*)d_in[3];
    const float* bias = (const float*)d_in[4];
    const float* w1   = (const float*)d_in[5];
    const float* b1   = (const float*)d_in[6];
    const float* w2   = (const float*)d_in[7];
    const float* b2   = (const float*)d_in[8];
    const float* pa   = (const float*)d_in[9];
    const float* gw   = (const float*)d_in[10];
    const float* gb   = (const float*)d_in[11];
    const float* gms  = (const float*)d_in[12];
    float* out = (float*)d_out;

    int N = in_sizes[0] / IN_C;
    int E = in_sizes[2] / EDIM;
    int total = N * OUT_C;
    int nbN = (N + 255) / 256;
    int nbE = (E + 255) / 256;

    // common prefix
    char* p = (char*)d_ws;
    u64*   degcnt = (u64*)p;  p += sizeof(u64) * (size_t)N;
    float* dinv   = (float*)p; p += sizeof(float) * (size_t)N;
    __half* xts   = (__half*)p; p += sizeof(__half) * (size_t)N * OUT_C;
    float* sums   = (float*)p; p += sizeof(float) * 128;
    int*   cnt    = (int*)p;   p += sizeof(int) * (size_t)N;
    char*  tail = p;
    // CSR-direct layout
    u64*   ovfcnt  = (u64*)tail;
    int4*  ovflist = (int4*)(tail + sizeof(u64) * 2);
    u32*   rec     = (u32*)(tail + sizeof(u64) * 2 + sizeof(int4) * OVFCAP);
    size_t need_csr = (size_t)((char*)(rec + (size_t)N * MAXDEG) - (char*)d_ws);
    // fallback layout (aliases tail)
    int2*  tmp = (int2*)tail;
    bool use_csr = (need_csr <= ws_size);

    if (use_csr) {
        k_init  <<<nbN, 256, 0, stream>>>(degcnt, sums, ovfcnt, N);
        k_edge  <<<nbE, 256, 0, stream>>>(ea, ei, w1, b1, w2, b2, degcnt,
                                          rec, ovfcnt, ovflist, E);
        k_xt    <<<(N + 63) / 64, 256, 0, stream>>>(x, lw, degcnt, xts, N);
        k_gather<<<(N + 15) / 16, 256, 0, stream>>>(rec, degcnt, (const uint2*)xts,
                                                    (const float4*)bias, (float4*)out, N);
        k_ovf   <<<64, 256, 0, stream>>>(ovflist, ovfcnt, degcnt, xts, out);
        k_stats <<<512, 256, 0, stream>>>(out, pa, sums, total);
        k_apply <<<(total + 255) / 256, 256, 0, stream>>>(out, pa, sums, gw, gb, gms,
                                                          total, 1.0f / (float)N);
    } else {
        k_init   <<<nbN, 256, 0, stream>>>(degcnt, sums, (u64*)sums /*dummy*/, N);
        k_edge_fb<<<nbE, 256, 0, stream>>>(ea, ei, w1, b1, w2, b2, degcnt, tmp, E);
        k_finish <<<nbN, 256, 0, stream>>>(degcnt, dinv, cnt, N);
        k_xt     <<<(N + 63) / 64, 256, 0, stream>>>(x, lw, degcnt, xts, N);
        k_init_out<<<(total + 255) / 256, 256, 0, stream>>>(bias, dinv, xts, out, total);
        long st = (long)E * 64;
        k_scatter <<<(unsigned)((st + 255) / 256), 256, 0, stream>>>(ei, tmp, dinv, xts, out, E);
        k_stats  <<<512, 256, 0, stream>>>(out, pa, sums, total);
        k_apply  <<<(total + 255) / 256, 256, 0, stream>>>(out, pa, sums, gw, gb, gms,
                                                           total, 1.0f / (float)N);
    }
}